// Round 1
// baseline (5851.983 us; speedup 1.0000x reference)
//
#include <hip/hip_runtime.h>
#include <hip/hip_bf16.h>

#define NLAYERS 6
#define Bc 2
#define Tc 13294
#define Ec 256
#define NHc 8
#define HDc 32
#define Lc 4
#define NPc 4
#define FFNc 1024

// epilogue kinds
#define EPI_BIAS 0
#define EPI_MASK 1
#define EPI_RES  2
#define EPI_RELU 3

// ---------------- LayerNorm (+ optional q = x + pos) ----------------
// one wave (64 lanes) per row of 256; block = 4 waves
__global__ __launch_bounds__(256) void ln_kernel(
    const float* __restrict__ src, const float* __restrict__ pos,
    const float* __restrict__ g, const float* __restrict__ b,
    float* __restrict__ x, float* __restrict__ q, int rows)
{
    int wave = threadIdx.x >> 6;
    int lane = threadIdx.x & 63;
    int row = blockIdx.x * 4 + wave;
    if (row >= rows) return;
    const float* p = src + (size_t)row * Ec;
    float4 v = *(const float4*)(p + lane * 4);
    float s  = v.x + v.y + v.z + v.w;
    float sq = v.x*v.x + v.y*v.y + v.z*v.z + v.w*v.w;
    #pragma unroll
    for (int o = 32; o; o >>= 1) { s += __shfl_xor(s, o); sq += __shfl_xor(sq, o); }
    float mean = s * (1.f / Ec);
    float var  = sq * (1.f / Ec) - mean * mean;
    float inv  = rsqrtf(var + 1e-5f);
    float4 gg = *(const float4*)(g + lane * 4);
    float4 bb = *(const float4*)(b + lane * 4);
    float4 xo;
    xo.x = (v.x - mean) * inv * gg.x + bb.x;
    xo.y = (v.y - mean) * inv * gg.y + bb.y;
    xo.z = (v.z - mean) * inv * gg.z + bb.z;
    xo.w = (v.w - mean) * inv * gg.w + bb.w;
    *(float4*)(x + (size_t)row * Ec + lane * 4) = xo;
    if (q) {
        float4 pp = *(const float4*)(pos + (size_t)row * Ec + lane * 4);
        float4 qo;
        qo.x = xo.x + pp.x; qo.y = xo.y + pp.y;
        qo.z = xo.z + pp.z; qo.w = xo.w + pp.w;
        *(float4*)(q + (size_t)row * Ec + lane * 4) = qo;
    }
}

// ---------------- tiled fp32 GEMM: C = A(MxK) @ B(KxN) + bias, epilogue ----------------
// BM=BN=64, BK=16, 256 threads, 4x4 per thread
template<int EPI>
__global__ __launch_bounds__(256) void gemm64(
    const float* __restrict__ A, const float* __restrict__ Bw,
    const float* __restrict__ bias, const float* res,
    const unsigned char* __restrict__ mask,
    float* C, int M, int N, int K)
{
    __shared__ float As[16][68];
    __shared__ float Bs[16][68];
    const int row0 = blockIdx.x * 64;
    const int col0 = blockIdx.y * 64;
    const int tid = threadIdx.x;
    const int tr = tid >> 4, tc = tid & 15;
    float acc[4][4] = {};

    for (int k0 = 0; k0 < K; k0 += 16) {
        {   // A tile: 64 rows x 16 k
            int kk = tid & 15;
            int rbase = tid >> 4;
            #pragma unroll
            for (int i = 0; i < 4; ++i) {
                int r = rbase + i * 16;
                int grow = row0 + r;
                float v = 0.f;
                if (grow < M) v = A[(size_t)grow * K + k0 + kk];
                As[kk][r] = v;
            }
        }
        {   // B tile: 16 k x 64 cols
            int c = tid & 63;
            int kb = tid >> 6;
            #pragma unroll
            for (int i = 0; i < 4; ++i) {
                int kk = kb + i * 4;
                Bs[kk][c] = Bw[(size_t)(k0 + kk) * N + col0 + c];
            }
        }
        __syncthreads();
        #pragma unroll
        for (int k = 0; k < 16; ++k) {
            float4 a4 = *(const float4*)&As[k][tr * 4];
            float4 b4 = *(const float4*)&Bs[k][tc * 4];
            float av[4] = {a4.x, a4.y, a4.z, a4.w};
            float bv_[4] = {b4.x, b4.y, b4.z, b4.w};
            #pragma unroll
            for (int i = 0; i < 4; ++i)
                #pragma unroll
                for (int j = 0; j < 4; ++j)
                    acc[i][j] = fmaf(av[i], bv_[j], acc[i][j]);
        }
        __syncthreads();
    }

    #pragma unroll
    for (int i = 0; i < 4; ++i) {
        int grow = row0 + tr * 4 + i;
        if (grow >= M) continue;
        #pragma unroll
        for (int j = 0; j < 4; ++j) {
            int gcol = col0 + tc * 4 + j;
            float v = acc[i][j] + bias[gcol];
            if (EPI == EPI_MASK) { if (mask[grow]) v = 0.f; }
            if (EPI == EPI_RES)  { v += res[(size_t)grow * N + gcol]; }
            if (EPI == EPI_RELU) { v = v > 0.f ? v : 0.f; }
            C[(size_t)grow * N + gcol] = v;
        }
    }
}

// ---------------- softmax over groups of 16 ----------------
__global__ __launch_bounds__(256) void softmax16(float* attn, int n)
{
    int i = blockIdx.x * 256 + threadIdx.x;
    if (i >= n) return;
    float* p = attn + (size_t)i * 16;
    float v[16];
    #pragma unroll
    for (int j = 0; j < 16; ++j) v[j] = p[j];
    float m = v[0];
    #pragma unroll
    for (int j = 1; j < 16; ++j) m = fmaxf(m, v[j]);
    float s = 0.f;
    #pragma unroll
    for (int j = 0; j < 16; ++j) { v[j] = expf(v[j] - m); s += v[j]; }
    float r = 1.f / s;
    #pragma unroll
    for (int j = 0; j < 16; ++j) p[j] = v[j] * r;
}

// ---------------- MSDA: multi-scale deformable attention sampling ----------------
// one 32-lane group per (b, q, h); lane = d
__global__ __launch_bounds__(256) void msda_kernel(
    const float* __restrict__ value, const float* __restrict__ off,
    const float* __restrict__ attn, const float* __restrict__ vr,
    float* __restrict__ out, int nGroups)
{
    int gidx = blockIdx.x * 8 + (threadIdx.x >> 5);
    if (gidx >= nGroups) return;
    int d = threadIdx.x & 31;
    int h = gidx & (NHc - 1);
    int bq = gidx >> 3;           // b*T + q
    int qq = bq % Tc;
    int b = bq / Tc;

    const int Wl[4] = {100, 50, 25, 13};
    const int Hl[4] = {100, 50, 25, 13};
    const int St[4] = {0, 10000, 12500, 13125};

    int qlvl, qi;
    if (qq < 10000)      { qlvl = 0; qi = qq; }
    else if (qq < 12500) { qlvl = 1; qi = qq - 10000; }
    else if (qq < 13125) { qlvl = 2; qi = qq - 12500; }
    else                 { qlvl = 3; qi = qq - 13125; }

    float base_x = (0.5f + (float)(qi % Wl[qlvl])) / (vr[(b * Lc + qlvl) * 2 + 0] * (float)Wl[qlvl]);
    float base_y = (0.5f + (float)(qi / Wl[qlvl])) / (vr[(b * Lc + qlvl) * 2 + 1] * (float)Hl[qlvl]);

    const float* offp = off  + (size_t)bq * 256 + h * 32;
    const float* attp = attn + (size_t)bq * 128 + h * 16;

    float acc = 0.f;
    #pragma unroll
    for (int lvl = 0; lvl < 4; ++lvl) {
        const int w = Wl[lvl], hh = Hl[lvl], st = St[lvl];
        float refx = base_x * vr[(b * Lc + lvl) * 2 + 0];
        float refy = base_y * vr[(b * Lc + lvl) * 2 + 1];
        const float* vbase = value + ((size_t)(b * Tc + st)) * 256 + h * 32 + d;
        #pragma unroll
        for (int p = 0; p < 4; ++p) {
            float ox = offp[(lvl * 4 + p) * 2 + 0];
            float oy = offp[(lvl * 4 + p) * 2 + 1];
            float aw = attp[lvl * 4 + p];
            float locx = refx + ox / (float)w;
            float locy = refy + oy / (float)hh;
            float xf = locx * (float)w - 0.5f;
            float yf = locy * (float)hh - 0.5f;
            float x0f = floorf(xf), y0f = floorf(yf);
            int x0 = (int)x0f, y0 = (int)y0f;
            float wx = xf - x0f, wy = yf - y0f;
            float samp = 0.f;
            // (x0, y0)
            if (x0 >= 0 && x0 < w && y0 >= 0 && y0 < hh)
                samp += (1.f - wx) * (1.f - wy) * vbase[(size_t)(y0 * w + x0) * 256];
            // (x0+1, y0)
            if (x0 + 1 >= 0 && x0 + 1 < w && y0 >= 0 && y0 < hh)
                samp += wx * (1.f - wy) * vbase[(size_t)(y0 * w + x0 + 1) * 256];
            // (x0, y0+1)
            if (x0 >= 0 && x0 < w && y0 + 1 >= 0 && y0 + 1 < hh)
                samp += (1.f - wx) * wy * vbase[(size_t)((y0 + 1) * w + x0) * 256];
            // (x0+1, y0+1)
            if (x0 + 1 >= 0 && x0 + 1 < w && y0 + 1 >= 0 && y0 + 1 < hh)
                samp += wx * wy * vbase[(size_t)((y0 + 1) * w + x0 + 1) * 256];
            acc = fmaf(aw, samp, acc);
        }
    }
    out[(size_t)bq * 256 + h * 32 + d] = acc;
}

extern "C" void kernel_launch(void* const* d_in, const int* in_sizes, int n_in,
                              void* d_out, int out_size, void* d_ws, size_t ws_size,
                              hipStream_t stream) {
    const float* src  = (const float*)d_in[0];
    const float* pos  = (const float*)d_in[1];
    const float* vr   = (const float*)d_in[2];
    const unsigned char* mask = (const unsigned char*)d_in[5];
    const float* Wv    = (const float*)d_in[6];
    const float* bv    = (const float*)d_in[7];
    const float* Woff  = (const float*)d_in[8];
    const float* boff  = (const float*)d_in[9];
    const float* Wattn = (const float*)d_in[10];
    const float* battn = (const float*)d_in[11];
    const float* Wout  = (const float*)d_in[12];
    const float* bout  = (const float*)d_in[13];
    const float* n1g   = (const float*)d_in[14];
    const float* n1b   = (const float*)d_in[15];
    const float* n2g   = (const float*)d_in[16];
    const float* n2b   = (const float*)d_in[17];
    const float* W1    = (const float*)d_in[18];
    const float* b1    = (const float*)d_in[19];
    const float* W2    = (const float*)d_in[20];
    const float* b2    = (const float*)d_in[21];
    float* out = (float*)d_out;
    float* ws = (float*)d_ws;

    const size_t R = (size_t)Bc * Tc;   // 26588 rows
    float* x    = ws;                   // R*256
    float* q    = x + R * 256;          // R*256
    float* val  = q + R * 256;          // R*256
    float* offb = val + R * 256;        // R*256
    float* attn = offb + R * 256;       // R*128
    float* msda = attn + R * 128;       // R*256
    float* srcb = msda + R * 256;       // R*256
    float* hbuf = x;                    // aliases x..offb = R*1024 (dead at FFN time)

    const int lnBlocks = (int)((R + 3) / 4);
    const int rowTiles = (int)((R + 63) / 64);
    dim3 g256(rowTiles, 4);
    dim3 g128(rowTiles, 2);
    dim3 g1024(rowTiles, 16);
    const int nGroups = (int)(R * NHc);

    for (int l = 0; l < NLAYERS; ++l) {
        const float* cur = (l == 0) ? src : srcb;
        // LN1 + q = x + pos
        ln_kernel<<<lnBlocks, 256, 0, stream>>>(cur, pos, n1g + l * Ec, n1b + l * Ec, x, q, (int)R);
        // value = x @ Wv + bv, mask->0
        gemm64<EPI_MASK><<<g256, 256, 0, stream>>>(x, Wv + (size_t)l * Ec * Ec, bv + l * Ec,
                                                   nullptr, mask, val, (int)R, Ec, Ec);
        // off = q @ Woff + boff
        gemm64<EPI_BIAS><<<g256, 256, 0, stream>>>(q, Woff + (size_t)l * Ec * 256, boff + l * 256,
                                                   nullptr, nullptr, offb, (int)R, 256, Ec);
        // attn logits = q @ Wattn + battn
        gemm64<EPI_BIAS><<<g128, 256, 0, stream>>>(q, Wattn + (size_t)l * Ec * 128, battn + l * 128,
                                                   nullptr, nullptr, attn, (int)R, 128, Ec);
        // softmax over 16
        softmax16<<<(nGroups + 255) / 256, 256, 0, stream>>>(attn, nGroups);
        // MSDA
        msda_kernel<<<(nGroups + 7) / 8, 256, 0, stream>>>(val, offb, attn, vr, msda, nGroups);
        // src2 = src + msda @ Wout + bout
        gemm64<EPI_RES><<<g256, 256, 0, stream>>>(msda, Wout + (size_t)l * Ec * Ec, bout + l * Ec,
                                                  cur, nullptr, srcb, (int)R, Ec, Ec);
        // LN2 -> x2 (stored in msda buffer)
        ln_kernel<<<lnBlocks, 256, 0, stream>>>(srcb, nullptr, n2g + l * Ec, n2b + l * Ec, msda, nullptr, (int)R);
        // h = relu(x2 @ W1 + b1)
        gemm64<EPI_RELU><<<g1024, 256, 0, stream>>>(msda, W1 + (size_t)l * Ec * FFNc, b1 + l * FFNc,
                                                    nullptr, nullptr, hbuf, (int)R, FFNc, Ec);
        // src = src2 + h @ W2 + b2
        float* dst = (l == NLAYERS - 1) ? out : srcb;
        gemm64<EPI_RES><<<g256, 256, 0, stream>>>(hbuf, W2 + (size_t)l * FFNc * Ec, b2 + l * Ec,
                                                  srcb, nullptr, dst, (int)R, Ec, FFNc);
    }
}

// Round 2
// 1706.951 us; speedup vs baseline: 3.4283x; 3.4283x over previous
//
#include <hip/hip_runtime.h>
#include <hip/hip_bf16.h>

#define NLAYERS 6
#define Bc 2
#define Tc 13294
#define Ec 256
#define NHc 8
#define HDc 32
#define FFNc 1024

#define EPI_BIAS 0
#define EPI_MASK 1
#define EPI_RES  2
#define EPI_RELU 3

typedef __attribute__((ext_vector_type(8))) short bf16x8;
typedef __attribute__((ext_vector_type(4))) float f32x4;

__device__ __forceinline__ short f2bf(float f) {
    union { float f; unsigned u; } v; v.f = f;
    unsigned r = v.u + 0x7FFFu + ((v.u >> 16) & 1u);
    return (short)(r >> 16);
}
__device__ __forceinline__ float bf2f(short s) {
    union { unsigned u; float f; } v; v.u = ((unsigned)(unsigned short)s) << 16;
    return v.f;
}

// ---------------- LayerNorm (+ optional q = x + pos), bf16 outputs ----------------
__global__ __launch_bounds__(256) void ln_kernel(
    const float* __restrict__ src, const float* __restrict__ pos,
    const float* __restrict__ g, const float* __restrict__ b,
    short* __restrict__ x, short* __restrict__ q, int rows)
{
    int wave = threadIdx.x >> 6;
    int lane = threadIdx.x & 63;
    int row = blockIdx.x * 4 + wave;
    if (row >= rows) return;
    const float* p = src + (size_t)row * Ec;
    float4 v = *(const float4*)(p + lane * 4);
    float s  = v.x + v.y + v.z + v.w;
    float sq = v.x*v.x + v.y*v.y + v.z*v.z + v.w*v.w;
    #pragma unroll
    for (int o = 32; o; o >>= 1) { s += __shfl_xor(s, o); sq += __shfl_xor(sq, o); }
    float mean = s * (1.f / Ec);
    float var  = sq * (1.f / Ec) - mean * mean;
    float inv  = rsqrtf(var + 1e-5f);
    float4 gg = *(const float4*)(g + lane * 4);
    float4 bb = *(const float4*)(b + lane * 4);
    float xo0 = (v.x - mean) * inv * gg.x + bb.x;
    float xo1 = (v.y - mean) * inv * gg.y + bb.y;
    float xo2 = (v.z - mean) * inv * gg.z + bb.z;
    float xo3 = (v.w - mean) * inv * gg.w + bb.w;
    short4 xs; xs.x = f2bf(xo0); xs.y = f2bf(xo1); xs.z = f2bf(xo2); xs.w = f2bf(xo3);
    *(short4*)(x + (size_t)row * Ec + lane * 4) = xs;
    if (q) {
        float4 pp = *(const float4*)(pos + (size_t)row * Ec + lane * 4);
        short4 qs;
        qs.x = f2bf(xo0 + pp.x); qs.y = f2bf(xo1 + pp.y);
        qs.z = f2bf(xo2 + pp.z); qs.w = f2bf(xo3 + pp.w);
        *(short4*)(q + (size_t)row * Ec + lane * 4) = qs;
    }
}

// ---------------- weight transpose+convert: W[K][N] fp32 -> Wt[N][K] bf16 ----------------
__global__ __launch_bounds__(256) void transpose_w(
    const float* __restrict__ W, short* __restrict__ Wt, int K, int N)
{
    __shared__ float tile[32][33];
    int l = blockIdx.z;
    const float* Wl = W + (size_t)l * K * N;
    short* Wtl = Wt + (size_t)l * K * N;
    int n0 = blockIdx.x * 32, k0 = blockIdx.y * 32;
    int tx = threadIdx.x & 31, ty = threadIdx.x >> 5;
    #pragma unroll
    for (int i = 0; i < 32; i += 8)
        tile[ty + i][tx] = Wl[(size_t)(k0 + ty + i) * N + n0 + tx];
    __syncthreads();
    #pragma unroll
    for (int i = 0; i < 32; i += 8)
        Wtl[(size_t)(n0 + ty + i) * K + k0 + tx] = f2bf(tile[tx][ty + i]);
}

// ---------------- bf16 MFMA GEMM: C = A(MxK,bf16) @ Bt(NxK,bf16)^T + bias, epilogue ----------------
// 128x128 tile, BK=32, 256 threads (4 waves, each 64x64)
template<int EPI, int OBF>
__global__ __launch_bounds__(256) void gemm_mfma(
    const short* __restrict__ A, const short* __restrict__ Bt,
    const float* __restrict__ bias, const float* __restrict__ res,
    const unsigned char* __restrict__ mask, void* __restrict__ Cout,
    int M, int N, int K)
{
    __shared__ short As[128 * 40];
    __shared__ short Bs[128 * 40];
    const int tid = threadIdx.x;
    const int lane = tid & 63;
    const int wv = tid >> 6;
    const int row0 = blockIdx.x * 128;
    const int col0 = blockIdx.y * 128;
    const int mbase = (wv >> 1) * 64;
    const int nbase = (wv & 1) * 64;
    const int lr = lane & 15;
    const int kg = lane >> 4;

    f32x4 zf = {0.f, 0.f, 0.f, 0.f};
    f32x4 acc[4][4];
    #pragma unroll
    for (int i = 0; i < 4; ++i)
        #pragma unroll
        for (int j = 0; j < 4; ++j) acc[i][j] = zf;

    const int srow = tid >> 1;
    const int koff = (tid & 1) * 16;
    const bool arow_ok = (row0 + srow) < M;
    const short* Aptr = A + (size_t)(row0 + srow) * K + koff;
    const short* Bptr = Bt + (size_t)(col0 + srow) * K + koff;
    short* awp = &As[srow * 40 + koff];
    short* bwp = &Bs[srow * 40 + koff];

    for (int k0 = 0; k0 < K; k0 += 32) {
        uint4 a1 = {0,0,0,0}, a2 = {0,0,0,0};
        if (arow_ok) {
            a1 = *(const uint4*)(Aptr + k0);
            a2 = *(const uint4*)(Aptr + k0 + 8);
        }
        uint4 b1 = *(const uint4*)(Bptr + k0);
        uint4 b2 = *(const uint4*)(Bptr + k0 + 8);
        __syncthreads();
        *(uint4*)awp = a1; *(uint4*)(awp + 8) = a2;
        *(uint4*)bwp = b1; *(uint4*)(bwp + 8) = b2;
        __syncthreads();
        bf16x8 af[4], bfr[4];
        #pragma unroll
        for (int i = 0; i < 4; ++i) {
            af[i]  = *(const bf16x8*)&As[(mbase + i * 16 + lr) * 40 + kg * 8];
            bfr[i] = *(const bf16x8*)&Bs[(nbase + i * 16 + lr) * 40 + kg * 8];
        }
        #pragma unroll
        for (int mi = 0; mi < 4; ++mi)
            #pragma unroll
            for (int ni = 0; ni < 4; ++ni)
                acc[mi][ni] = __builtin_amdgcn_mfma_f32_16x16x32_bf16(
                    af[mi], bfr[ni], acc[mi][ni], 0, 0, 0);
    }

    float* Cf = (float*)Cout;
    short* Cb = (short*)Cout;
    #pragma unroll
    for (int ni = 0; ni < 4; ++ni) {
        int col = col0 + nbase + ni * 16 + lr;
        float bz = bias[col];
        #pragma unroll
        for (int mi = 0; mi < 4; ++mi) {
            int rb = row0 + mbase + mi * 16 + kg * 4;
            #pragma unroll
            for (int j = 0; j < 4; ++j) {
                int grow = rb + j;
                if (grow >= M) continue;
                float v = acc[mi][ni][j] + bz;
                if (EPI == EPI_MASK) { if (mask[grow]) v = 0.f; }
                if (EPI == EPI_RES)  v += res[(size_t)grow * N + col];
                if (EPI == EPI_RELU) v = v > 0.f ? v : 0.f;
                if (OBF) Cb[(size_t)grow * N + col] = f2bf(v);
                else     Cf[(size_t)grow * N + col] = v;
            }
        }
    }
}

// ---------------- softmax over groups of 16 ----------------
__global__ __launch_bounds__(256) void softmax16(float* attn, int n)
{
    int i = blockIdx.x * 256 + threadIdx.x;
    if (i >= n) return;
    float* p = attn + (size_t)i * 16;
    float v[16];
    #pragma unroll
    for (int j = 0; j < 16; ++j) v[j] = p[j];
    float m = v[0];
    #pragma unroll
    for (int j = 1; j < 16; ++j) m = fmaxf(m, v[j]);
    float s = 0.f;
    #pragma unroll
    for (int j = 0; j < 16; ++j) { v[j] = expf(v[j] - m); s += v[j]; }
    float r = 1.f / s;
    #pragma unroll
    for (int j = 0; j < 16; ++j) p[j] = v[j] * r;
}

// ---------------- MSDA: phase1 = per-point math on 16 lanes, phase2 = gathers ----------------
// group = 32 lanes = one (b,q,h); 8 groups/block; grid = R blocks exactly
__global__ __launch_bounds__(256) void msda_kernel(
    const short* __restrict__ value, const float* __restrict__ off,
    const float* __restrict__ attn, const float* __restrict__ vr,
    short* __restrict__ out)
{
    __shared__ int pts[8][16][8];
    const int group = threadIdx.x >> 5;
    const int l32 = threadIdx.x & 31;
    const int gidx = blockIdx.x * 8 + group;
    const int h = gidx & 7;
    const int bq = gidx >> 3;
    const int b = (bq >= Tc) ? 1 : 0;
    const int qq = bq - b * Tc;

    if (l32 < 16) {
        const int p = l32;
        const int lvl = p >> 2;
        const int Wl[4] = {100, 50, 25, 13};
        const int St[4] = {0, 10000, 12500, 13125};
        float base_x, base_y;
        if (qq < 10000) {
            int qi = qq;
            base_x = (0.5f + (float)(qi % 100)) / (vr[(b*4+0)*2+0] * 100.f);
            base_y = (0.5f + (float)(qi / 100)) / (vr[(b*4+0)*2+1] * 100.f);
        } else if (qq < 12500) {
            int qi = qq - 10000;
            base_x = (0.5f + (float)(qi % 50)) / (vr[(b*4+1)*2+0] * 50.f);
            base_y = (0.5f + (float)(qi / 50)) / (vr[(b*4+1)*2+1] * 50.f);
        } else if (qq < 13125) {
            int qi = qq - 12500;
            base_x = (0.5f + (float)(qi % 25)) / (vr[(b*4+2)*2+0] * 25.f);
            base_y = (0.5f + (float)(qi / 25)) / (vr[(b*4+2)*2+1] * 25.f);
        } else {
            int qi = qq - 13125;
            base_x = (0.5f + (float)(qi % 13)) / (vr[(b*4+3)*2+0] * 13.f);
            base_y = (0.5f + (float)(qi / 13)) / (vr[(b*4+3)*2+1] * 13.f);
        }
        const int w = Wl[lvl], hh = Wl[lvl];
        const float refx = base_x * vr[(b*4+lvl)*2+0];
        const float refy = base_y * vr[(b*4+lvl)*2+1];
        const float ox = off[(size_t)bq * 256 + h * 32 + p * 2 + 0];
        const float oy = off[(size_t)bq * 256 + h * 32 + p * 2 + 1];
        const float aw = attn[(size_t)bq * 128 + h * 16 + p];
        float locx = refx + ox / (float)w;
        float locy = refy + oy / (float)hh;
        float xf = locx * (float)w - 0.5f;
        float yf = locy * (float)hh - 0.5f;
        float x0f = floorf(xf), y0f = floorf(yf);
        int x0 = (int)x0f, y0 = (int)y0f;
        float wx = xf - x0f, wy = yf - y0f;
        float w00 = (1.f - wx) * (1.f - wy) * aw;
        float w10 = wx * (1.f - wy) * aw;
        float w01 = (1.f - wx) * wy * aw;
        float w11 = wx * wy * aw;
        bool vx0 = (x0 >= 0) && (x0 < w);
        bool vx1 = (x0 + 1 >= 0) && (x0 + 1 < w);
        bool vy0 = (y0 >= 0) && (y0 < hh);
        bool vy1 = (y0 + 1 >= 0) && (y0 + 1 < hh);
        if (!(vx0 && vy0)) w00 = 0.f;
        if (!(vx1 && vy0)) w10 = 0.f;
        if (!(vx0 && vy1)) w01 = 0.f;
        if (!(vx1 && vy1)) w11 = 0.f;
        int cx0 = min(max(x0, 0), w - 1), cx1 = min(max(x0 + 1, 0), w - 1);
        int cy0 = min(max(y0, 0), hh - 1), cy1 = min(max(y0 + 1, 0), hh - 1);
        int rowbase = b * Tc + St[lvl];
        pts[group][p][0] = __float_as_int(w00);
        pts[group][p][1] = __float_as_int(w10);
        pts[group][p][2] = __float_as_int(w01);
        pts[group][p][3] = __float_as_int(w11);
        pts[group][p][4] = ((rowbase + cy0 * w + cx0) * 8 + h) * 32;
        pts[group][p][5] = ((rowbase + cy0 * w + cx1) * 8 + h) * 32;
        pts[group][p][6] = ((rowbase + cy1 * w + cx0) * 8 + h) * 32;
        pts[group][p][7] = ((rowbase + cy1 * w + cx1) * 8 + h) * 32;
    }
    __syncthreads();

    const int d = l32;
    float acc = 0.f;
    #pragma unroll
    for (int p = 0; p < 16; ++p) {
        int4 wq = *(const int4*)&pts[group][p][0];
        int4 aq = *(const int4*)&pts[group][p][4];
        float v00 = bf2f(value[aq.x + d]);
        float v10 = bf2f(value[aq.y + d]);
        float v01 = bf2f(value[aq.z + d]);
        float v11 = bf2f(value[aq.w + d]);
        acc = fmaf(__int_as_float(wq.x), v00, acc);
        acc = fmaf(__int_as_float(wq.y), v10, acc);
        acc = fmaf(__int_as_float(wq.z), v01, acc);
        acc = fmaf(__int_as_float(wq.w), v11, acc);
    }
    out[(size_t)bq * 256 + h * 32 + d] = f2bf(acc);
}

extern "C" void kernel_launch(void* const* d_in, const int* in_sizes, int n_in,
                              void* d_out, int out_size, void* d_ws, size_t ws_size,
                              hipStream_t stream) {
    const float* src  = (const float*)d_in[0];
    const float* pos  = (const float*)d_in[1];
    const float* vr   = (const float*)d_in[2];
    const unsigned char* mask = (const unsigned char*)d_in[5];
    const float* Wv    = (const float*)d_in[6];
    const float* bv    = (const float*)d_in[7];
    const float* Woff  = (const float*)d_in[8];
    const float* boff  = (const float*)d_in[9];
    const float* Wattn = (const float*)d_in[10];
    const float* battn = (const float*)d_in[11];
    const float* Wout  = (const float*)d_in[12];
    const float* bout  = (const float*)d_in[13];
    const float* n1g   = (const float*)d_in[14];
    const float* n1b   = (const float*)d_in[15];
    const float* n2g   = (const float*)d_in[16];
    const float* n2b   = (const float*)d_in[17];
    const float* W1    = (const float*)d_in[18];
    const float* b1    = (const float*)d_in[19];
    const float* W2    = (const float*)d_in[20];
    const float* b2    = (const float*)d_in[21];
    float* out = (float*)d_out;

    const size_t R = (size_t)Bc * Tc;   // 26588

    // bf16 activation block (shorts); hb aliases xb..msdab (all dead by FFN1)
    short* xb    = (short*)d_ws;          // R*256
    short* qb    = xb + R * 256;          // R*256
    short* valb  = qb + R * 256;          // R*256
    short* msdab = valb + R * 256;        // R*256
    short* hb    = xb;                    // R*1024 alias
    short* ln2b  = msdab + R * 256;       // R*256
    // fp32 buffers
    float* offb  = (float*)(ln2b + R * 256);  // R*256
    float* attnb = offb + R * 256;            // R*128
    float* srcb  = attnb + R * 128;           // R*256
    // bf16 transposed weights
    short* wvT    = (short*)(srcb + R * 256);     // 6*65536
    short* woffT  = wvT + 6 * 65536;
    short* wattnT = woffT + 6 * 65536;            // 6*32768
    short* woutT  = wattnT + 6 * 32768;           // 6*65536
    short* w1T    = woutT + 6 * 65536;            // 6*262144 ([1024][256])
    short* w2T    = w1T + 6 * 262144;             // 6*262144 ([256][1024])

    // one-time weight transpose+convert (grid.x = N/32, grid.y = K/32)
    transpose_w<<<dim3(8, 8, 6),  256, 0, stream>>>(Wv,    wvT,    256, 256);
    transpose_w<<<dim3(8, 8, 6),  256, 0, stream>>>(Woff,  woffT,  256, 256);
    transpose_w<<<dim3(4, 8, 6),  256, 0, stream>>>(Wattn, wattnT, 256, 128);
    transpose_w<<<dim3(8, 8, 6),  256, 0, stream>>>(Wout,  woutT,  256, 256);
    transpose_w<<<dim3(32, 8, 6), 256, 0, stream>>>(W1,    w1T,    256, 1024);
    transpose_w<<<dim3(8, 32, 6), 256, 0, stream>>>(W2,    w2T,    1024, 256);

    const int lnBlocks = (int)((R + 3) / 4);
    const int MT = (int)((R + 127) / 128);  // 208
    const int nGroups = (int)(R * NHc);

    for (int l = 0; l < NLAYERS; ++l) {
        const float* cur = (l == 0) ? src : srcb;
        // LN1 -> x (bf16), q = x + pos (bf16)
        ln_kernel<<<lnBlocks, 256, 0, stream>>>(cur, pos, n1g + l * Ec, n1b + l * Ec, xb, qb, (int)R);
        // value = x @ Wv + bv, mask->0, bf16 out
        gemm_mfma<EPI_MASK, 1><<<dim3(MT, 2), 256, 0, stream>>>(
            xb, wvT + (size_t)l * 65536, bv + l * Ec, nullptr, mask, valb, (int)R, 256, 256);
        // off = q @ Woff + boff (fp32)
        gemm_mfma<EPI_BIAS, 0><<<dim3(MT, 2), 256, 0, stream>>>(
            qb, woffT + (size_t)l * 65536, boff + l * 256, nullptr, nullptr, offb, (int)R, 256, 256);
        // attn logits = q @ Wattn + battn (fp32)
        gemm_mfma<EPI_BIAS, 0><<<dim3(MT, 1), 256, 0, stream>>>(
            qb, wattnT + (size_t)l * 32768, battn + l * 128, nullptr, nullptr, attnb, (int)R, 128, 256);
        // softmax over 16
        softmax16<<<(nGroups + 255) / 256, 256, 0, stream>>>(attnb, nGroups);
        // MSDA -> bf16
        msda_kernel<<<(int)R, 256, 0, stream>>>(valb, offb, attnb, vr, msdab);
        // src2 = src + msda @ Wout + bout (fp32)
        gemm_mfma<EPI_RES, 0><<<dim3(MT, 2), 256, 0, stream>>>(
            msdab, woutT + (size_t)l * 65536, bout + l * Ec, cur, nullptr, srcb, (int)R, 256, 256);
        // LN2 -> bf16
        ln_kernel<<<lnBlocks, 256, 0, stream>>>(srcb, nullptr, n2g + l * Ec, n2b + l * Ec, ln2b, nullptr, (int)R);
        // h = relu(x2 @ W1 + b1) (bf16)
        gemm_mfma<EPI_RELU, 1><<<dim3(MT, 8), 256, 0, stream>>>(
            ln2b, w1T + (size_t)l * 262144, b1 + l * FFNc, nullptr, nullptr, hb, (int)R, 1024, 256);
        // out = src2 + h @ W2 + b2 (fp32)
        float* dst = (l == NLAYERS - 1) ? out : srcb;
        gemm_mfma<EPI_RES, 0><<<dim3(MT, 2), 256, 0, stream>>>(
            hb, w2T + (size_t)l * 262144, b2 + l * Ec, srcb, nullptr, dst, (int)R, 256, 1024);
    }
}

// Round 3
// 1452.433 us; speedup vs baseline: 4.0291x; 1.1752x over previous
//
#include <hip/hip_runtime.h>
#include <hip/hip_bf16.h>

#define NLAYERS 6
#define Bc 2
#define Tc 13294
#define Ec 256
#define NHc 8
#define FFNc 1024

#define EPI_BIAS 0
#define EPI_MASK 1
#define EPI_RES  2
#define EPI_RELU 3

typedef __attribute__((ext_vector_type(8))) short bf16x8;
typedef __attribute__((ext_vector_type(4))) float f32x4;

typedef __attribute__((address_space(3))) unsigned int u32_lds;
typedef __attribute__((address_space(1))) unsigned int u32_glb;

__device__ __forceinline__ void gld16(const void* g, void* l) {
    __builtin_amdgcn_global_load_lds((const u32_glb*)g, (u32_lds*)l, 16, 0, 0);
}

__device__ __forceinline__ short f2bf(float f) {
    union { float f; unsigned u; } v; v.f = f;
    unsigned r = v.u + 0x7FFFu + ((v.u >> 16) & 1u);
    return (short)(r >> 16);
}
__device__ __forceinline__ float bf_lo(unsigned u) {
    union { unsigned u; float f; } v; v.u = u << 16; return v.f;
}
__device__ __forceinline__ float bf_hi(unsigned u) {
    union { unsigned u; float f; } v; v.u = u & 0xFFFF0000u; return v.f;
}

// ---------------- LayerNorm (+ optional q = x + pos), bf16 outputs ----------------
__global__ __launch_bounds__(256) void ln_kernel(
    const float* __restrict__ src, const float* __restrict__ pos,
    const float* __restrict__ g, const float* __restrict__ b,
    short* __restrict__ x, short* __restrict__ q, int rows)
{
    int wave = threadIdx.x >> 6;
    int lane = threadIdx.x & 63;
    int row = blockIdx.x * 4 + wave;
    if (row >= rows) return;
    const float* p = src + (size_t)row * Ec;
    float4 v = *(const float4*)(p + lane * 4);
    float s  = v.x + v.y + v.z + v.w;
    float sq = v.x*v.x + v.y*v.y + v.z*v.z + v.w*v.w;
    #pragma unroll
    for (int o = 32; o; o >>= 1) { s += __shfl_xor(s, o); sq += __shfl_xor(sq, o); }
    float mean = s * (1.f / Ec);
    float var  = sq * (1.f / Ec) - mean * mean;
    float inv  = rsqrtf(var + 1e-5f);
    float4 gg = *(const float4*)(g + lane * 4);
    float4 bb = *(const float4*)(b + lane * 4);
    float xo0 = (v.x - mean) * inv * gg.x + bb.x;
    float xo1 = (v.y - mean) * inv * gg.y + bb.y;
    float xo2 = (v.z - mean) * inv * gg.z + bb.z;
    float xo3 = (v.w - mean) * inv * gg.w + bb.w;
    short4 xs; xs.x = f2bf(xo0); xs.y = f2bf(xo1); xs.z = f2bf(xo2); xs.w = f2bf(xo3);
    *(short4*)(x + (size_t)row * Ec + lane * 4) = xs;
    if (q) {
        float4 pp = *(const float4*)(pos + (size_t)row * Ec + lane * 4);
        short4 qs;
        qs.x = f2bf(xo0 + pp.x); qs.y = f2bf(xo1 + pp.y);
        qs.z = f2bf(xo2 + pp.z); qs.w = f2bf(xo3 + pp.w);
        *(short4*)(q + (size_t)row * Ec + lane * 4) = qs;
    }
}

// ---------------- weight transpose+convert: W[K][N] fp32 -> Wt[rowOff+N][K] bf16 ----------------
__global__ __launch_bounds__(256) void transpose_w(
    const float* __restrict__ W, short* __restrict__ Wt, int K, int N,
    int layerStride, int rowOff)
{
    __shared__ float tile[32][33];
    int l = blockIdx.z;
    const float* Wl = W + (size_t)l * K * N;
    short* Wtl = Wt + (size_t)l * layerStride;
    int n0 = blockIdx.x * 32, k0 = blockIdx.y * 32;
    int tx = threadIdx.x & 31, ty = threadIdx.x >> 5;
    #pragma unroll
    for (int i = 0; i < 32; i += 8)
        tile[ty + i][tx] = Wl[(size_t)(k0 + ty + i) * N + n0 + tx];
    __syncthreads();
    #pragma unroll
    for (int i = 0; i < 32; i += 8)
        Wtl[(size_t)(rowOff + n0 + ty + i) * K + k0 + tx] = f2bf(tile[tx][ty + i]);
}

// ---------------- bf16 MFMA GEMM (m97 structure): 128x128 tile, BK=32 ----------------
// A: MxK bf16 row-major; Bt: NxK bf16 (pre-transposed); global_load_lds staging, linear LDS.
template<int EPI, int OBF>
__global__ __launch_bounds__(256) void gemm_mfma(
    const short* __restrict__ A, const short* __restrict__ Bt,
    const float* __restrict__ bias, const float* __restrict__ bias2,
    const float* __restrict__ res, const unsigned char* __restrict__ mask,
    void* __restrict__ Cout, int M, int N, int K)
{
    __shared__ short As[128 * 32];
    __shared__ short Bs[128 * 32];
    const int tid = threadIdx.x;
    const int lane = tid & 63;
    const int wv = tid >> 6;
    const int row0 = blockIdx.x * 128;
    const int col0 = blockIdx.y * 128;
    const int mbase = (wv >> 1) * 64;
    const int nbase = (wv & 1) * 64;
    const int lr = lane & 15;
    const int kg = lane >> 4;

    f32x4 zf = {0.f, 0.f, 0.f, 0.f};
    f32x4 acc[4][4];
    #pragma unroll
    for (int i = 0; i < 4; ++i)
        #pragma unroll
        for (int j = 0; j < 4; ++j) acc[i][j] = zf;

    // staging: wave wv stages rows [wv*32, wv*32+32) of each tile.
    // lane l -> row = wv*32 (+16) + l/4, col = (l%4)*8 shorts; LDS dest = wavebase + l*16 bytes.
    const int srow = wv * 32 + (lane >> 2);
    const int scol = (lane & 3) * 8;
    const short* Ap  = A  + (size_t)(row0 + srow) * K + scol;
    const short* Ap2 = Ap + (size_t)16 * K;
    const short* Bp  = Bt + (size_t)(col0 + srow) * K + scol;
    const short* Bp2 = Bp + (size_t)16 * K;
    short* Asw  = &As[srow * 32 + scol];
    short* Asw2 = Asw + 16 * 32;
    short* Bsw  = &Bs[srow * 32 + scol];
    short* Bsw2 = Bsw + 16 * 32;

    for (int k0 = 0; k0 < K; k0 += 32) {
        __syncthreads();
        gld16(Ap + k0,  Asw);
        gld16(Ap2 + k0, Asw2);
        gld16(Bp + k0,  Bsw);
        gld16(Bp2 + k0, Bsw2);
        __syncthreads();
        bf16x8 af[4], bfr[4];
        #pragma unroll
        for (int i = 0; i < 4; ++i) {
            af[i]  = *(const bf16x8*)&As[(mbase + i * 16 + lr) * 32 + kg * 8];
            bfr[i] = *(const bf16x8*)&Bs[(nbase + i * 16 + lr) * 32 + kg * 8];
        }
        #pragma unroll
        for (int mi = 0; mi < 4; ++mi)
            #pragma unroll
            for (int ni = 0; ni < 4; ++ni)
                acc[mi][ni] = __builtin_amdgcn_mfma_f32_16x16x32_bf16(
                    af[mi], bfr[ni], acc[mi][ni], 0, 0, 0);
    }

    float* Cf = (float*)Cout;
    short* Cb = (short*)Cout;
    #pragma unroll
    for (int ni = 0; ni < 4; ++ni) {
        int col = col0 + nbase + ni * 16 + lr;
        float bz = (bias2 && col >= 256) ? bias2[col - 256] : bias[col];
        #pragma unroll
        for (int mi = 0; mi < 4; ++mi) {
            int rb = row0 + mbase + mi * 16 + kg * 4;
            #pragma unroll
            for (int j = 0; j < 4; ++j) {
                int grow = rb + j;
                if (grow >= M) continue;
                float v = acc[mi][ni][j] + bz;
                if (EPI == EPI_MASK) { if (mask[grow]) v = 0.f; }
                if (EPI == EPI_RES)  v += res[(size_t)grow * N + col];
                if (EPI == EPI_RELU) v = v > 0.f ? v : 0.f;
                if (OBF) Cb[(size_t)grow * N + col] = f2bf(v);
                else     Cf[(size_t)grow * N + col] = v;
            }
        }
    }
}

// ---------------- MSDA with fused softmax ----------------
// group = 32 lanes = one (b,q,h); 8 groups/block; grid = R blocks.
// phase1 (lanes 0-15): softmax over 16 logits + per-point corner weights/byte-offsets -> LDS
// phase2: lane owns 2 dims (dword), half-wave owns 8 points; shfl_xor(16) combine.
__global__ __launch_bounds__(256) void msda_kernel(
    const short* __restrict__ value, const float* __restrict__ oa,
    const float* __restrict__ vr, short* __restrict__ out)
{
    __shared__ int pts[8][16][8];
    const int group = threadIdx.x >> 5;
    const int l32 = threadIdx.x & 31;
    const int gidx = blockIdx.x * 8 + group;
    const int h = gidx & 7;
    const int bq = gidx >> 3;
    const int b = (bq >= Tc) ? 1 : 0;
    const int qq = bq - b * Tc;

    if (l32 < 16) {
        const int p = l32;
        const int lvl = p >> 2;
        const int Wl[4] = {100, 50, 25, 13};
        const int St[4] = {0, 10000, 12500, 13125};
        float base_x, base_y;
        if (qq < 10000) {
            int qi = qq;
            base_x = (0.5f + (float)(qi % 100)) / (vr[(b*4+0)*2+0] * 100.f);
            base_y = (0.5f + (float)(qi / 100)) / (vr[(b*4+0)*2+1] * 100.f);
        } else if (qq < 12500) {
            int qi = qq - 10000;
            base_x = (0.5f + (float)(qi % 50)) / (vr[(b*4+1)*2+0] * 50.f);
            base_y = (0.5f + (float)(qi / 50)) / (vr[(b*4+1)*2+1] * 50.f);
        } else if (qq < 13125) {
            int qi = qq - 12500;
            base_x = (0.5f + (float)(qi % 25)) / (vr[(b*4+2)*2+0] * 25.f);
            base_y = (0.5f + (float)(qi / 25)) / (vr[(b*4+2)*2+1] * 25.f);
        } else {
            int qi = qq - 13125;
            base_x = (0.5f + (float)(qi % 13)) / (vr[(b*4+3)*2+0] * 13.f);
            base_y = (0.5f + (float)(qi / 13)) / (vr[(b*4+3)*2+1] * 13.f);
        }
        // softmax over the 16 logits (one per lane)
        float logit = oa[(size_t)bq * 384 + 256 + h * 16 + p];
        float mx = logit;
        #pragma unroll
        for (int o = 8; o; o >>= 1) mx = fmaxf(mx, __shfl_xor(mx, o));
        float e = expf(logit - mx);
        float sum = e;
        #pragma unroll
        for (int o = 8; o; o >>= 1) sum += __shfl_xor(sum, o);
        float aw = e / sum;

        const int w = Wl[lvl], hh = Wl[lvl];
        const float refx = base_x * vr[(b*4+lvl)*2+0];
        const float refy = base_y * vr[(b*4+lvl)*2+1];
        const float ox = oa[(size_t)bq * 384 + h * 32 + p * 2 + 0];
        const float oy = oa[(size_t)bq * 384 + h * 32 + p * 2 + 1];
        float locx = refx + ox / (float)w;
        float locy = refy + oy / (float)hh;
        float xf = locx * (float)w - 0.5f;
        float yf = locy * (float)hh - 0.5f;
        float x0f = floorf(xf), y0f = floorf(yf);
        int x0 = (int)x0f, y0 = (int)y0f;
        float wx = xf - x0f, wy = yf - y0f;
        float w00 = (1.f - wx) * (1.f - wy) * aw;
        float w10 = wx * (1.f - wy) * aw;
        float w01 = (1.f - wx) * wy * aw;
        float w11 = wx * wy * aw;
        bool vx0 = (x0 >= 0) && (x0 < w);
        bool vx1 = (x0 + 1 >= 0) && (x0 + 1 < w);
        bool vy0 = (y0 >= 0) && (y0 < hh);
        bool vy1 = (y0 + 1 >= 0) && (y0 + 1 < hh);
        if (!(vx0 && vy0)) w00 = 0.f;
        if (!(vx1 && vy0)) w10 = 0.f;
        if (!(vx0 && vy1)) w01 = 0.f;
        if (!(vx1 && vy1)) w11 = 0.f;
        int cx0 = min(max(x0, 0), w - 1), cx1 = min(max(x0 + 1, 0), w - 1);
        int cy0 = min(max(y0, 0), hh - 1), cy1 = min(max(y0 + 1, 0), hh - 1);
        int rowbase = b * Tc + St[lvl];
        // byte offsets of the 64B (h,32-dim) row for each corner
        pts[group][p][0] = __float_as_int(w00);
        pts[group][p][1] = __float_as_int(w10);
        pts[group][p][2] = __float_as_int(w01);
        pts[group][p][3] = __float_as_int(w11);
        pts[group][p][4] = (rowbase + cy0 * w + cx0) * 512 + h * 64;
        pts[group][p][5] = (rowbase + cy0 * w + cx1) * 512 + h * 64;
        pts[group][p][6] = (rowbase + cy1 * w + cx0) * 512 + h * 64;
        pts[group][p][7] = (rowbase + cy1 * w + cx1) * 512 + h * 64;
    }
    __syncthreads();

    const int d4 = (l32 & 15) * 4;          // byte offset of this lane's dim pair
    const int ph = (l32 >> 4) * 8;          // lanes 0-15: points 0-7; lanes 16-31: points 8-15
    const char* vbase = (const char*)value;
    float accL = 0.f, accH = 0.f;
    #pragma unroll
    for (int j = 0; j < 8; ++j) {
        int p = ph + j;
        int4 wq = *(const int4*)&pts[group][p][0];
        int4 aq = *(const int4*)&pts[group][p][4];
        unsigned u0 = *(const unsigned*)(vbase + (unsigned)(aq.x + d4));
        unsigned u1 = *(const unsigned*)(vbase + (unsigned)(aq.y + d4));
        unsigned u2 = *(const unsigned*)(vbase + (unsigned)(aq.z + d4));
        unsigned u3 = *(const unsigned*)(vbase + (unsigned)(aq.w + d4));
        float w00 = __int_as_float(wq.x), w10 = __int_as_float(wq.y);
        float w01 = __int_as_float(wq.z), w11 = __int_as_float(wq.w);
        accL = fmaf(w00, bf_lo(u0), accL); accH = fmaf(w00, bf_hi(u0), accH);
        accL = fmaf(w10, bf_lo(u1), accL); accH = fmaf(w10, bf_hi(u1), accH);
        accL = fmaf(w01, bf_lo(u2), accL); accH = fmaf(w01, bf_hi(u2), accH);
        accL = fmaf(w11, bf_lo(u3), accL); accH = fmaf(w11, bf_hi(u3), accH);
    }
    accL += __shfl_xor(accL, 16);
    accH += __shfl_xor(accH, 16);
    if (l32 < 16) {
        unsigned pk = ((unsigned)(unsigned short)f2bf(accL)) |
                      (((unsigned)(unsigned short)f2bf(accH)) << 16);
        *(unsigned*)((char*)out + (size_t)bq * 512 + h * 64 + d4) = pk;
    }
}

extern "C" void kernel_launch(void* const* d_in, const int* in_sizes, int n_in,
                              void* d_out, int out_size, void* d_ws, size_t ws_size,
                              hipStream_t stream) {
    const float* src  = (const float*)d_in[0];
    const float* pos  = (const float*)d_in[1];
    const float* vr   = (const float*)d_in[2];
    const unsigned char* mask = (const unsigned char*)d_in[5];
    const float* Wv    = (const float*)d_in[6];
    const float* bv    = (const float*)d_in[7];
    const float* Woff  = (const float*)d_in[8];
    const float* boff  = (const float*)d_in[9];
    const float* Wattn = (const float*)d_in[10];
    const float* battn = (const float*)d_in[11];
    const float* Wout  = (const float*)d_in[12];
    const float* bout  = (const float*)d_in[13];
    const float* n1g   = (const float*)d_in[14];
    const float* n1b   = (const float*)d_in[15];
    const float* n2g   = (const float*)d_in[16];
    const float* n2b   = (const float*)d_in[17];
    const float* W1    = (const float*)d_in[18];
    const float* b1    = (const float*)d_in[19];
    const float* W2    = (const float*)d_in[20];
    const float* b2    = (const float*)d_in[21];
    float* out = (float*)d_out;

    const size_t R = (size_t)Bc * Tc;   // 26588

    // bf16 activations; hb aliases xb..msdab (all dead by FFN1 time)
    short* xb    = (short*)d_ws;          // R*256
    short* qb    = xb + R * 256;
    short* valb  = qb + R * 256;
    short* msdab = valb + R * 256;
    short* hb    = xb;                    // R*1024 alias
    short* ln2b  = msdab + R * 256;       // R*256
    // fp32 buffers
    float* oab   = (float*)(ln2b + R * 256);  // R*384 (off 256 | attn logits 128)
    float* srcb  = oab + R * 384;             // R*256
    // bf16 transposed weights
    short* wvT   = (short*)(srcb + R * 256);  // 6*65536
    short* woaT  = wvT + 6 * 65536;           // 6*98304 ([384][256])
    short* woutT = woaT + 6 * 98304;          // 6*65536
    short* w1T   = woutT + 6 * 65536;         // 6*262144 ([1024][256])
    short* w2T   = w1T + 6 * 262144;          // 6*262144 ([256][1024])

    // one-time weight transpose+convert (grid: x=N/32, y=K/32, z=layers)
    transpose_w<<<dim3(8, 8, 6),  256, 0, stream>>>(Wv,    wvT,   256, 256,  65536, 0);
    transpose_w<<<dim3(8, 8, 6),  256, 0, stream>>>(Woff,  woaT,  256, 256,  98304, 0);
    transpose_w<<<dim3(4, 8, 6),  256, 0, stream>>>(Wattn, woaT,  256, 128,  98304, 256);
    transpose_w<<<dim3(8, 8, 6),  256, 0, stream>>>(Wout,  woutT, 256, 256,  65536, 0);
    transpose_w<<<dim3(32, 8, 6), 256, 0, stream>>>(W1,    w1T,   256, 1024, 262144, 0);
    transpose_w<<<dim3(8, 32, 6), 256, 0, stream>>>(W2,    w2T,   1024, 256, 262144, 0);

    const int lnBlocks = (int)((R + 3) / 4);
    const int MT = (int)((R + 127) / 128);  // 208

    for (int l = 0; l < NLAYERS; ++l) {
        const float* cur = (l == 0) ? src : srcb;
        // LN1 -> x (bf16), q = x + pos (bf16)
        ln_kernel<<<lnBlocks, 256, 0, stream>>>(cur, pos, n1g + l * Ec, n1b + l * Ec, xb, qb, (int)R);
        // value = x @ Wv + bv, mask->0, bf16
        gemm_mfma<EPI_MASK, 1><<<dim3(MT, 2), 256, 0, stream>>>(
            xb, wvT + (size_t)l * 65536, bv + l * Ec, nullptr, nullptr, mask, valb, (int)R, 256, 256);
        // [off | attn logits] = q @ [Woff|Wattn] + [boff|battn] (fp32, N=384)
        gemm_mfma<EPI_BIAS, 0><<<dim3(MT, 3), 256, 0, stream>>>(
            qb, woaT + (size_t)l * 98304, boff + l * 256, battn + l * 128, nullptr, nullptr,
            oab, (int)R, 384, 256);
        // MSDA (softmax fused) -> bf16
        msda_kernel<<<(int)R, 256, 0, stream>>>(valb, oab, vr, msdab);
        // src2 = src + msda @ Wout + bout (fp32)
        gemm_mfma<EPI_RES, 0><<<dim3(MT, 2), 256, 0, stream>>>(
            msdab, woutT + (size_t)l * 65536, bout + l * Ec, nullptr, cur, nullptr, srcb, (int)R, 256, 256);
        // LN2 -> bf16
        ln_kernel<<<lnBlocks, 256, 0, stream>>>(srcb, nullptr, n2g + l * Ec, n2b + l * Ec, ln2b, nullptr, (int)R);
        // h = relu(x2 @ W1 + b1) (bf16)
        gemm_mfma<EPI_RELU, 1><<<dim3(MT, 8), 256, 0, stream>>>(
            ln2b, w1T + (size_t)l * 262144, b1 + l * FFNc, nullptr, nullptr, nullptr, hb, (int)R, 1024, 256);
        // out = src2 + h @ W2 + b2 (fp32)
        float* dst = (l == NLAYERS - 1) ? out : srcb;
        gemm_mfma<EPI_RES, 0><<<dim3(MT, 2), 256, 0, stream>>>(
            hb, w2T + (size_t)l * 262144, b2 + l * Ec, nullptr, srcb, nullptr, dst, (int)R, 256, 1024);
    }
}